// Round 12
// baseline (285.963 us; speedup 1.0000x reference)
//
#include <hip/hip_runtime.h>
#include <math.h>

// ---------------------------------------------------------------------------
// GCN 165->32->16->2 + log_softmax, N=100k, E=3.2M.
//
// Round 22 (r21 + barrier-enforced src-window sweep in g1g2):
//  - r21 POST-MORTEM: gemm1 v4 good (out of top-5); total within noise of
//    best. g1g2 still 47us / 107MB FETCH vs 51MB cold floor (reuse 2.2x).
//  - r18's src-window sort gained only 10%: ~2 edges/window/lane -> threads
//    drift off lockstep immediately (600cy per miss). All 1563 blocks are
//    co-resident (24 waves/CU), so enforce the sweep:
//  - sort emits rowptr8[N][8] (window starts; free, from cur[] pre-scatter).
//  - g1g2 v5: 4 rounds x __syncthreads(); lane-h handles window 2k+h ->
//    <=2 of 7 windows active per block -> ~1.8MB table slice per XCD -> L2
//    resident. c-pair lanes unchanged (same edges, 64B line sharing).
//    OOB threads clamp to n=N-1 (same-value WAW) so barriers are uniform.
//  - Falsifier (binding): g1g2 FETCH > 95MB or dur >= 44us -> window
//    locality closed for good; attack place/sort next.
//  - place/sort-scatter/gemm1 v4/g2g3/final: r21 byte-identical.
// ---------------------------------------------------------------------------

constexpr int NT = 256;
constexpr int NPB = 256;       // nodes per bucket (partition)
constexpr int LOG_NPB = 8;
constexpr int MAXBUK = 512;
constexpr int BSTRIDE = 10240; // edge slots per bucket (mean 8184)
constexpr int NREP = 8;        // cursor replicas / subregions per bucket
constexpr int SUB = BSTRIDE / NREP;  // 1280 slots per subregion
constexpr int EPB_B = 4096;    // edges per block, place pass
constexpr int R = 8;           // src ranges (subkey) in sort
constexpr int RSH = 14;        // src>>14 -> 0..6 for N=100k

typedef __attribute__((ext_vector_type(8))) short bf16x8;
typedef __attribute__((ext_vector_type(4))) float f32x4;

__device__ inline unsigned short f2bf(float f) {  // RNE f32 -> bf16
    unsigned u = *(unsigned*)&f;
    u += 0x7fffu + ((u >> 16) & 1u);
    return (unsigned short)(u >> 16);
}
__device__ inline unsigned packbf(float a, float b) {
    return (unsigned)f2bf(a) | ((unsigned)f2bf(b) << 16);
}
// accumulate 8 bf16 (one uint4) into a[0..7]
__device__ inline void acc8(float* a, uint4 v) {
    const unsigned* u = (const unsigned*)&v;
#pragma unroll
    for (int w = 0; w < 4; w++) {
        unsigned lo = u[w] << 16, hi = u[w] & 0xffff0000u;
        a[2 * w]     += *(float*)&lo;
        a[2 * w + 1] += *(float*)&hi;
    }
}

__global__ __launch_bounds__(NT) void place_kernel(const int* __restrict__ src,
                                                   const int* __restrict__ dst,
                                                   int* __restrict__ cursor8,
                                                   unsigned* __restrict__ ebuf,
                                                   int E, int nbuk) {
    __shared__ int lh[MAXBUK];
    __shared__ int lbase[MAXBUK];
    for (int i = threadIdx.x; i < nbuk; i += NT) lh[i] = 0;
    __syncthreads();
    constexpr int EPT = EPB_B / NT;  // 16
    unsigned pk[EPT];
    unsigned bl[EPT];
    int base = blockIdx.x * EPB_B;
    int rep = blockIdx.x & (NREP - 1);
#pragma unroll
    for (int i = 0; i < EPT; i++) {
        int e = base + i * NT + threadIdx.x;
        if (e < E) {
            int s = src[e], d = dst[e];
            int b = d >> LOG_NPB;
            int lp = atomicAdd(&lh[b], 1);
            pk[i] = ((unsigned)(d & (NPB - 1)) << 24) | (unsigned)s;
            bl[i] = ((unsigned)b << 16) | (unsigned)lp;
        } else {
            bl[i] = 0xFFFFFFFFu;
        }
    }
    __syncthreads();
    for (int i = threadIdx.x; i < nbuk; i += NT) {
        int v = lh[i];
        if (v) lbase[i] = atomicAdd(&cursor8[rep * MAXBUK + i], v);
    }
    __syncthreads();
#pragma unroll
    for (int i = 0; i < EPT; i++) {
        if (bl[i] != 0xFFFFFFFFu) {
            int b = (int)(bl[i] >> 16);
            int pos = lbase[b] + (int)(bl[i] & 0xFFFFu);
            if (pos < SUB)
                ebuf[(size_t)b * BSTRIDE + rep * SUB + pos] = pk[i];
        }
    }
}

// One block per bucket (256 nodes). LDS-staged edges (ebuf read ONCE),
// counting sort over 2048 bins (local<<3 | src>>14). esrc per-node lists
// src-range-ordered. Thread tid owns node tid's 8 bins. Emits rowptr8
// (per-node window starts) for g1g2's barriered sweep.
__global__ __launch_bounds__(NT) void sort_kernel(
    const unsigned* __restrict__ ebuf, const int* __restrict__ cursor8,
    int* __restrict__ esrc, int* __restrict__ rowptr, int* __restrict__ rowcnt,
    int* __restrict__ rowptr8, float* __restrict__ dinv, int N) {
    __shared__ unsigned se[BSTRIDE];   // 40KB staged edges
    __shared__ int cnt[NPB * R];       // 8KB
    __shared__ int cur[NPB * R];       // 8KB
    __shared__ int psum[NT];           // 1KB
    int tid = threadIdx.x;
    int b = blockIdx.x;
    for (int i = tid; i < NPB * R; i += NT) cnt[i] = 0;
    __syncthreads();
    int scnt[NREP], sofs[NREP];
    int total = 0;
#pragma unroll
    for (int r = 0; r < NREP; r++) {
        int v = min(cursor8[r * MAXBUK + b], SUB);
        scnt[r] = v; sofs[r] = total; total += v;
    }
#pragma unroll
    for (int r = 0; r < NREP; r++) {
        int e0 = b * BSTRIDE + r * SUB;
        for (int i = tid; i < scnt[r]; i += NT) {
            unsigned p = ebuf[e0 + i];
            se[sofs[r] + i] = p;
            atomicAdd(&cnt[(p >> 24) * R + ((p & 0xFFFFFFu) >> RSH)], 1);
        }
    }
    __syncthreads();
    int loc[R];
    int s = 0;
#pragma unroll
    for (int i = 0; i < R; i++) { loc[i] = s; s += cnt[tid * R + i]; }
    psum[tid] = s;
    __syncthreads();
    for (int off = 1; off < NPB; off <<= 1) {
        int a = (tid >= off) ? psum[tid - off] : 0;
        __syncthreads();
        psum[tid] += a;
        __syncthreads();
    }
    int excl = psum[tid] - s;
#pragma unroll
    for (int i = 0; i < R; i++) cur[tid * R + i] = excl + loc[i];
    {
        int n = b * NPB + tid;
        if (n < N) {
            rowptr[n] = b * BSTRIDE + excl;
            rowcnt[n] = s;
            dinv[n] = rsqrtf((float)s + 1.0f);
#pragma unroll
            for (int i = 0; i < R; i++)
                rowptr8[(size_t)n * 8 + i] = b * BSTRIDE + excl + loc[i];
        }
    }
    __syncthreads();
    for (int i = tid; i < total; i += NT) {
        unsigned p = se[i];
        unsigned sidx = p & 0xFFFFFFu;
        int bin = (int)(p >> 24) * R + (int)(sidx >> RSH);
        int pos = atomicAdd(&cur[bin], 1);
        esrc[b * BSTRIDE + pos] = (int)sidx;
    }
}

// Layer 1 GEMM 165->32 via MFMA 16x16x32 bf16. One wave per 16-node tile,
// 4 tiles (64 nodes) per block. v4: x slab + W1^T staged into LDS COALESCED
// (bf16, rows padded to 200 -> 16B-aligned ds_read_b128 fragments).
__global__ __launch_bounds__(NT) void gemm1_mfma(
    const float* __restrict__ in, const float* __restrict__ W,
    const float* __restrict__ dinv, uint4* __restrict__ hs, int Ntot) {
    constexpr int DIN = 165;
    constexpr int RP = 200;                  // padded row length (bf16)
    __shared__ unsigned short xs[64 * RP];   // 25.6KB staged x slab
    __shared__ unsigned short ws[32 * RP];   // 12.8KB staged W1^T
    __shared__ float tile[4][16][36];        // 9.2KB epilogue transpose
    int ntiles = (Ntot + 15) >> 4;
    int slab0 = (blockIdx.x * 4) << 4;       // first node of this 64-row slab
    int rows = min(64, Ntot - slab0);
    // zero the pad zones (k in [165,200)) of xs and ws
    for (int i = threadIdx.x; i < (64 + 32) * (RP - DIN); i += NT) {
        int r = i / (RP - DIN);
        int k = DIN + (i - r * (RP - DIN));
        if (r < 64) xs[r * RP + k] = 0;
        else        ws[(r - 64) * RP + k] = 0;
    }
    // stage x rows: global idx linear (slab0*DIN + i) -> fully coalesced
    {
        const float* xbase = in + (size_t)slab0 * DIN;
        int tot = rows * DIN;
        for (int i = threadIdx.x; i < tot; i += NT) {
            int r = i / DIN;
            xs[i + r * (RP - DIN)] = f2bf(xbase[i]);
        }
    }
    // stage W1 transposed: read W[i] linear (i = k*32+col) -> coalesced
    for (int i = threadIdx.x; i < DIN * 32; i += NT) {
        int k = i >> 5;
        int col = i & 31;
        ws[col * RP + k] = f2bf(W[i]);
    }
    __syncthreads();
    int lane = threadIdx.x & 63;
    int wv = threadIdx.x >> 6;
    int t = blockIdx.x * 4 + wv;
    if (t >= ntiles) return;
    int n0 = t << 4;
    int mrow = lane & 15;
    int quad = lane >> 4;
    int arow = n0 + mrow;
    if (arow >= Ntot) arow = Ntot - 1;  // clamp (stays within staged slab)
    int lrow = arow - slab0;            // LDS row in [0,64)
    f32x4 acc0 = {0.f, 0.f, 0.f, 0.f};
    f32x4 acc1 = {0.f, 0.f, 0.f, 0.f};
#pragma unroll
    for (int c = 0; c < 6; c++) {
        int kb = c * 32 + quad * 8;     // max 184; [165,200) zero-padded
        union { bf16x8 v; unsigned short u[8]; } A, B0, B1;
        __builtin_memcpy(&A.v,  &xs[lrow * RP + kb], 16);
        __builtin_memcpy(&B0.v, &ws[mrow * RP + kb], 16);
        __builtin_memcpy(&B1.v, &ws[(16 + mrow) * RP + kb], 16);
        acc0 = __builtin_amdgcn_mfma_f32_16x16x32_bf16(A.v, B0.v, acc0, 0, 0, 0);
        acc1 = __builtin_amdgcn_mfma_f32_16x16x32_bf16(A.v, B1.v, acc1, 0, 0, 0);
    }
#pragma unroll
    for (int r = 0; r < 4; r++) {
        tile[wv][quad * 4 + r][mrow] = acc0[r];
        tile[wv][quad * 4 + r][16 + mrow] = acc1[r];
    }
    int node = lane >> 2;
    int part = lane & 3;          // features part*8 .. part*8+7
    int n = n0 + node;
    if (n >= Ntot) return;
    float dv = dinv[n];
    float f[8];
#pragma unroll
    for (int i = 0; i < 8; i++) f[i] = tile[wv][node][part * 8 + i];
    unsigned u0 = packbf(dv * f[0], dv * f[1]);
    unsigned u1 = packbf(dv * f[2], dv * f[3]);
    unsigned u2 = packbf(dv * f[4], dv * f[5]);
    unsigned u3 = packbf(dv * f[6], dv * f[7]);
    hs[(size_t)n * 4 + part] = make_uint4(u0, u1, u2, u3);
}

// Fused layer-1 gather + relu(dv*agg+b1) + 32->16 GEMM + bf16 message pack.
// v5 (barriered window sweep): 4 lanes/node, c = feature half (2 uint4 =
// 32B; c-pair lanes walk identical edges -> 64B line sharing), h = window
// parity. 4 rounds; round k: lane-h processes src-window 2k+h, then
// __syncthreads(). <=2 windows (~1.8MB table) active per block at a time.
// OOB threads clamp to n=N-1 (same-value WAW; barriers stay uniform).
__global__ __launch_bounds__(NT) void g1g2_kernel(
    const uint4* __restrict__ hsb, const int* __restrict__ esrc,
    const int* __restrict__ rowptr8, const int* __restrict__ rowcnt,
    const float* __restrict__ dinv, const float* __restrict__ b1,
    const float* __restrict__ W2 /*[32][16]*/, uint4* __restrict__ hs2b,
    int N) {
    __shared__ float sW[32 * 16];
    __shared__ float sb[32];
    for (int i = threadIdx.x; i < 32 * 16; i += NT) sW[i] = W2[i];
    if (threadIdx.x < 32) sb[threadIdx.x] = b1[threadIdx.x];
    __syncthreads();
    int gid = blockIdx.x * NT + threadIdx.x;
    int n = gid >> 2;
    int q = gid & 3;
    int c = q & 1;
    int h = q >> 1;
    bool alive = (n < N);
    if (!alive) n = N - 1;   // clamp: duplicate lanes recompute same node
    int rp[9];
    {
        const int* rpp = rowptr8 + (size_t)n * 8;
#pragma unroll
        for (int i = 0; i < 8; i++) rp[i] = rpp[i];
        rp[8] = rp[0] + rowcnt[n];
    }
    float a[16];
    if (h == 0) {  // self-loop message
        const uint4* hp = hsb + (size_t)n * 4 + c * 2;
        uint4 v0 = hp[0], v1 = hp[1];
        const unsigned* u0 = (const unsigned*)&v0;
        const unsigned* u1 = (const unsigned*)&v1;
#pragma unroll
        for (int w = 0; w < 4; w++) {
            unsigned lo = u0[w] << 16, hi = u0[w] & 0xffff0000u;
            a[2 * w] = *(float*)&lo; a[2 * w + 1] = *(float*)&hi;
            unsigned lo1 = u1[w] << 16, hi1 = u1[w] & 0xffff0000u;
            a[8 + 2 * w] = *(float*)&lo1; a[8 + 2 * w + 1] = *(float*)&hi1;
        }
    } else {
#pragma unroll
        for (int k = 0; k < 16; k++) a[k] = 0.f;
    }
    // 4 rounds x (window 2k+h) with block-level lockstep
    for (int k = 0; k < 4; k++) {
        int w = 2 * k + h;
        int j = rp[w], jend = rp[w + 1];
        for (; j + 3 < jend; j += 4) {
            int s0 = esrc[j], s1 = esrc[j + 1], s2 = esrc[j + 2], s3 = esrc[j + 3];
            uint4 v00 = hsb[(size_t)s0 * 4 + c * 2], v01 = hsb[(size_t)s0 * 4 + c * 2 + 1];
            uint4 v10 = hsb[(size_t)s1 * 4 + c * 2], v11 = hsb[(size_t)s1 * 4 + c * 2 + 1];
            uint4 v20 = hsb[(size_t)s2 * 4 + c * 2], v21 = hsb[(size_t)s2 * 4 + c * 2 + 1];
            uint4 v30 = hsb[(size_t)s3 * 4 + c * 2], v31 = hsb[(size_t)s3 * 4 + c * 2 + 1];
            acc8(a, v00); acc8(a + 8, v01);
            acc8(a, v10); acc8(a + 8, v11);
            acc8(a, v20); acc8(a + 8, v21);
            acc8(a, v30); acc8(a + 8, v31);
        }
        for (; j < jend; j++) {
            int s = esrc[j];
            acc8(a, hsb[(size_t)s * 4 + c * 2]);
            acc8(a + 8, hsb[(size_t)s * 4 + c * 2 + 1]);
        }
        __syncthreads();   // lockstep: whole block advances to next windows
    }
    // combine window-parity halves (lane +-2): full aggregation before relu
#pragma unroll
    for (int k = 0; k < 16; k++) a[k] += __shfl_xor(a[k], 2);
    float dv = dinv[n];
    float z[16];
#pragma unroll
    for (int d = 0; d < 16; d++) z[d] = 0.f;
#pragma unroll
    for (int k = 0; k < 16; k++) {
        float f = fmaxf(fmaf(dv, a[k], sb[c * 16 + k]), 0.f);
#pragma unroll
        for (int d = 0; d < 16; d++)
            z[d] = fmaf(f, sW[(c * 16 + k) * 16 + d], z[d]);
    }
    // combine feature halves (lane +-1): full z on all 4 lanes
#pragma unroll
    for (int d = 0; d < 16; d++) z[d] += __shfl_xor(z[d], 1);
    if (h == 0) {  // lane c packs outputs c*8 .. c*8+7 (message = dv * z)
        unsigned u0 = packbf(dv * z[c * 8 + 0], dv * z[c * 8 + 1]);
        unsigned u1 = packbf(dv * z[c * 8 + 2], dv * z[c * 8 + 3]);
        unsigned u2 = packbf(dv * z[c * 8 + 4], dv * z[c * 8 + 5]);
        unsigned u3 = packbf(dv * z[c * 8 + 6], dv * z[c * 8 + 7]);
        hs2b[(size_t)n * 2 + c] = make_uint4(u0, u1, u2, u3);
    }
}

// Fused layer-2 gather + relu(dv*agg+b2) + 16->2 GEMM -> hs3 (f32 [N][2]).
// 4 lanes/node: c = feature half (one uint4, 16B; c-pair shares 32B),
// h = edge half. Combine pattern as r18.
__global__ __launch_bounds__(NT) void g2g3_kernel(
    const uint4* __restrict__ hs2b, const int* __restrict__ esrc,
    const int* __restrict__ rowptr, const int* __restrict__ rowcnt,
    const float* __restrict__ dinv, const float* __restrict__ b2,
    const float* __restrict__ W3 /*[16][2]*/, float* __restrict__ hs3,
    int N) {
    __shared__ float sW[32];
    __shared__ float sb[16];
    if (threadIdx.x < 32) sW[threadIdx.x] = W3[threadIdx.x];
    if (threadIdx.x < 16) sb[threadIdx.x] = b2[threadIdx.x];
    __syncthreads();
    int gid = blockIdx.x * NT + threadIdx.x;
    int n = gid >> 2;
    int q = gid & 3;
    int c = q & 1;
    int h = q >> 1;
    if (n >= N) return;
    int start = rowptr[n];
    int cnt = rowcnt[n];
    int half0 = (cnt + 1) >> 1;
    int j    = start + (h ? half0 : 0);
    int jend = start + (h ? cnt : half0);
    float a[8];
    if (h == 0) {  // self-loop message
        uint4 v = hs2b[(size_t)n * 2 + c];
        const unsigned* u = (const unsigned*)&v;
#pragma unroll
        for (int w = 0; w < 4; w++) {
            unsigned lo = u[w] << 16, hi = u[w] & 0xffff0000u;
            a[2 * w] = *(float*)&lo; a[2 * w + 1] = *(float*)&hi;
        }
    } else {
#pragma unroll
        for (int k = 0; k < 8; k++) a[k] = 0.f;
    }
    for (; j + 3 < jend; j += 4) {
        uint4 v0 = hs2b[(size_t)esrc[j] * 2 + c];
        uint4 v1 = hs2b[(size_t)esrc[j + 1] * 2 + c];
        uint4 v2 = hs2b[(size_t)esrc[j + 2] * 2 + c];
        uint4 v3 = hs2b[(size_t)esrc[j + 3] * 2 + c];
        acc8(a, v0); acc8(a, v1); acc8(a, v2); acc8(a, v3);
    }
    for (; j < jend; j++) acc8(a, hs2b[(size_t)esrc[j] * 2 + c]);
    // combine edge halves before relu
#pragma unroll
    for (int k = 0; k < 8; k++) a[k] += __shfl_xor(a[k], 2);
    float dv = dinv[n];
    float z0 = 0.f, z1 = 0.f;
#pragma unroll
    for (int k = 0; k < 8; k++) {
        float f = fmaxf(fmaf(dv, a[k], sb[c * 8 + k]), 0.f);
        z0 = fmaf(f, sW[(c * 8 + k) * 2 + 0], z0);
        z1 = fmaf(f, sW[(c * 8 + k) * 2 + 1], z1);
    }
    z0 += __shfl_xor(z0, 1);
    z1 += __shfl_xor(z1, 1);
    if (q == 0) {
        hs3[(size_t)n * 2 + 0] = dv * z0;
        hs3[(size_t)n * 2 + 1] = dv * z1;
    }
}

// Layer 3 gather (hs3 0.8MB, L2-resident) + bias + log_softmax.
// 2 lanes/node, contiguous edge halves, shfl_xor(1) combine.
__global__ __launch_bounds__(NT) void final_kernel(
    const float* __restrict__ hs3, const int* __restrict__ esrc,
    const int* __restrict__ rowptr, const int* __restrict__ rowcnt,
    const float* __restrict__ dinv, const float* __restrict__ b,
    float* __restrict__ out, int N) {
    int gid = blockIdx.x * NT + threadIdx.x;
    int n = gid >> 1;
    int h = gid & 1;
    if (n >= N) return;
    int start = rowptr[n];
    int cnt = rowcnt[n];
    int half0 = (cnt + 1) >> 1;
    int j    = start + (h ? half0 : 0);
    int jend = start + (h ? cnt : half0);
    const float2* h2 = (const float2*)hs3;
    float2 acc = h ? make_float2(0.f, 0.f) : h2[n];  // self-loop on h=0
    for (; j + 3 < jend; j += 4) {
        float2 v0 = h2[esrc[j]], v1 = h2[esrc[j + 1]];
        float2 v2 = h2[esrc[j + 2]], v3 = h2[esrc[j + 3]];
        acc.x += v0.x + v1.x + v2.x + v3.x;
        acc.y += v0.y + v1.y + v2.y + v3.y;
    }
    for (; j < jend; j++) {
        float2 v = h2[esrc[j]];
        acc.x += v.x; acc.y += v.y;
    }
    acc.x += __shfl_xor(acc.x, 1);
    acc.y += __shfl_xor(acc.y, 1);
    if (h == 0) {
        float dv = dinv[n];
        float z0 = fmaf(dv, acc.x, b[0]);
        float z1 = fmaf(dv, acc.y, b[1]);
        float m = fmaxf(z0, z1);
        float lse = m + logf(expf(z0 - m) + expf(z1 - m));
        out[(size_t)n * 2 + 0] = z0 - lse;
        out[(size_t)n * 2 + 1] = z1 - lse;
    }
}

extern "C" void kernel_launch(void* const* d_in, const int* in_sizes, int n_in,
                              void* d_out, int out_size, void* d_ws, size_t ws_size,
                              hipStream_t stream) {
    const float* x  = (const float*)d_in[0];
    const int*   ei = (const int*)d_in[1];
    const float* W1 = (const float*)d_in[2];
    const float* b1 = (const float*)d_in[3];
    const float* W2 = (const float*)d_in[4];
    const float* b2 = (const float*)d_in[5];
    const float* W3 = (const float*)d_in[6];
    const float* b3 = (const float*)d_in[7];
    float* out = (float*)d_out;

    const int N = in_sizes[0] / 165;  // 100000
    const int E = in_sizes[1] / 2;    // 3200000
    const int* src = ei;
    const int* dst = ei + E;
    const int nbuk = (N + NPB - 1) >> LOG_NPB;  // 391
    const int G4 = ((size_t)N * 4 + NT - 1) / NT;  // 4 lanes/node dispatches
    const int G2 = ((size_t)N * 2 + NT - 1) / NT;  // 2 lanes/node dispatches

    char* p = (char*)d_ws;
    int* cursor8   = (int*)p;      p += (size_t)NREP * MAXBUK * 4;
    unsigned* ebuf = (unsigned*)p; p += (size_t)nbuk * BSTRIDE * 4;
    int* esrc      = (int*)p;      p += (size_t)nbuk * BSTRIDE * 4;
    int* rowptr    = (int*)p;      p += (size_t)N * 4;
    int* rowcnt    = (int*)p;      p += (size_t)N * 4;
    int* rowptr8   = (int*)p;      p += (size_t)N * 8 * 4;
    float* dinv    = (float*)p;    p += (size_t)N * 4;
    uint4* hs1b    = (uint4*)p;    p += (size_t)N * 4 * 16;  // bf16 [N][4]uint4
    uint4* hs2b    = (uint4*)p;    p += (size_t)N * 2 * 16;  // bf16 [N][2]uint4
    float* hs3     = (float*)p;    p += (size_t)N * 2 * 4;   // f32 [N][2]

    (void)hipMemsetAsync(cursor8, 0, (size_t)NREP * MAXBUK * sizeof(int), stream);
    place_kernel<<<(E + EPB_B - 1) / EPB_B, NT, 0, stream>>>(src, dst, cursor8, ebuf, E, nbuk);
    sort_kernel<<<nbuk, NT, 0, stream>>>(ebuf, cursor8, esrc, rowptr, rowcnt, rowptr8, dinv, N);

    // Layer 1: 165 -> 32 MFMA, bf16 messages (one 64B line per node)
    gemm1_mfma<<<((N + 15) / 16 + 3) / 4, NT, 0, stream>>>(x, W1, dinv, hs1b, N);

    // Layer 1 gather + layer 2 GEMM fused (4 lanes/node, barriered windows)
    g1g2_kernel<<<G4, NT, 0, stream>>>(hs1b, esrc, rowptr8, rowcnt, dinv, b1, W2, hs2b, N);

    // Layer 2 gather + layer 3 GEMM fused (4 lanes/node)
    g2g3_kernel<<<G4, NT, 0, stream>>>(hs2b, esrc, rowptr, rowcnt, dinv, b2, W3, hs3, N);

    // Layer 3 gather + bias + log_softmax (2 lanes/node)
    final_kernel<<<G2, NT, 0, stream>>>(hs3, esrc, rowptr, rowcnt, dinv, b3, out, N);
}

// Round 13
// 272.900 us; speedup vs baseline: 1.0479x; 1.0479x over previous
//
#include <hip/hip_runtime.h>
#include <math.h>

// ---------------------------------------------------------------------------
// GCN 165->32->16->2 + log_softmax, N=100k, E=3.2M.
//
// Round 23 (r21 base + isolated g2g3-8lane / final-4lane):
//  - r22 POST-MORTEM: window sweep hit predicted FETCH floor (64MB) but
//    TIME rose (53us) — 3rd proof g1g2 is MLP-limited: locality schemes
//    that constrain scheduling lose. g1g2 closed at ~46us permanently.
//  - r20 bundled g2g3-8lane/final-4lane with a bad gemm1 variant; never
//    isolated. r14 precedent (2x concurrency on latency-bound gather =
//    -16%) predicts they help: g2g3 table 3.2MB L2-resident, final 0.8MB.
//  - This round: exact r21 + g2g3 8 lanes/node (2 feat x 4 edge-quarters,
//    shfl_xor(2)+(4) then (1)) + final 4 lanes/node (quarters, (1)+(2)).
//  - Falsifier (binding): total >= 276us -> all edge kernels at latency
//    walls -> declare ROOFLINE next round.
//  - place/sort/gemm1 v4/g1g2: r21 byte-identical.
// ---------------------------------------------------------------------------

constexpr int NT = 256;
constexpr int NPB = 256;       // nodes per bucket (partition)
constexpr int LOG_NPB = 8;
constexpr int MAXBUK = 512;
constexpr int BSTRIDE = 10240; // edge slots per bucket (mean 8184)
constexpr int NREP = 8;        // cursor replicas / subregions per bucket
constexpr int SUB = BSTRIDE / NREP;  // 1280 slots per subregion
constexpr int EPB_B = 4096;    // edges per block, place pass
constexpr int R = 8;           // src ranges (subkey) in sort
constexpr int RSH = 14;        // src>>14 -> 0..6 for N=100k

typedef __attribute__((ext_vector_type(8))) short bf16x8;
typedef __attribute__((ext_vector_type(4))) float f32x4;

__device__ inline unsigned short f2bf(float f) {  // RNE f32 -> bf16
    unsigned u = *(unsigned*)&f;
    u += 0x7fffu + ((u >> 16) & 1u);
    return (unsigned short)(u >> 16);
}
__device__ inline unsigned packbf(float a, float b) {
    return (unsigned)f2bf(a) | ((unsigned)f2bf(b) << 16);
}
// accumulate 8 bf16 (one uint4) into a[0..7]
__device__ inline void acc8(float* a, uint4 v) {
    const unsigned* u = (const unsigned*)&v;
#pragma unroll
    for (int w = 0; w < 4; w++) {
        unsigned lo = u[w] << 16, hi = u[w] & 0xffff0000u;
        a[2 * w]     += *(float*)&lo;
        a[2 * w + 1] += *(float*)&hi;
    }
}

__global__ __launch_bounds__(NT) void place_kernel(const int* __restrict__ src,
                                                   const int* __restrict__ dst,
                                                   int* __restrict__ cursor8,
                                                   unsigned* __restrict__ ebuf,
                                                   int E, int nbuk) {
    __shared__ int lh[MAXBUK];
    __shared__ int lbase[MAXBUK];
    for (int i = threadIdx.x; i < nbuk; i += NT) lh[i] = 0;
    __syncthreads();
    constexpr int EPT = EPB_B / NT;  // 16
    unsigned pk[EPT];
    unsigned bl[EPT];
    int base = blockIdx.x * EPB_B;
    int rep = blockIdx.x & (NREP - 1);
#pragma unroll
    for (int i = 0; i < EPT; i++) {
        int e = base + i * NT + threadIdx.x;
        if (e < E) {
            int s = src[e], d = dst[e];
            int b = d >> LOG_NPB;
            int lp = atomicAdd(&lh[b], 1);
            pk[i] = ((unsigned)(d & (NPB - 1)) << 24) | (unsigned)s;
            bl[i] = ((unsigned)b << 16) | (unsigned)lp;
        } else {
            bl[i] = 0xFFFFFFFFu;
        }
    }
    __syncthreads();
    for (int i = threadIdx.x; i < nbuk; i += NT) {
        int v = lh[i];
        if (v) lbase[i] = atomicAdd(&cursor8[rep * MAXBUK + i], v);
    }
    __syncthreads();
#pragma unroll
    for (int i = 0; i < EPT; i++) {
        if (bl[i] != 0xFFFFFFFFu) {
            int b = (int)(bl[i] >> 16);
            int pos = lbase[b] + (int)(bl[i] & 0xFFFFu);
            if (pos < SUB)
                ebuf[(size_t)b * BSTRIDE + rep * SUB + pos] = pk[i];
        }
    }
}

// One block per bucket (256 nodes). LDS-staged edges (ebuf read ONCE),
// counting sort over 2048 bins (local<<3 | src>>14). esrc per-node lists
// src-range-ordered. Thread tid owns node tid's 8 bins.
__global__ __launch_bounds__(NT) void sort_kernel(
    const unsigned* __restrict__ ebuf, const int* __restrict__ cursor8,
    int* __restrict__ esrc, int* __restrict__ rowptr, int* __restrict__ rowcnt,
    float* __restrict__ dinv, int N) {
    __shared__ unsigned se[BSTRIDE];   // 40KB staged edges
    __shared__ int cnt[NPB * R];       // 8KB
    __shared__ int cur[NPB * R];       // 8KB
    __shared__ int psum[NT];           // 1KB
    int tid = threadIdx.x;
    int b = blockIdx.x;
    for (int i = tid; i < NPB * R; i += NT) cnt[i] = 0;
    __syncthreads();
    int scnt[NREP], sofs[NREP];
    int total = 0;
#pragma unroll
    for (int r = 0; r < NREP; r++) {
        int v = min(cursor8[r * MAXBUK + b], SUB);
        scnt[r] = v; sofs[r] = total; total += v;
    }
#pragma unroll
    for (int r = 0; r < NREP; r++) {
        int e0 = b * BSTRIDE + r * SUB;
        for (int i = tid; i < scnt[r]; i += NT) {
            unsigned p = ebuf[e0 + i];
            se[sofs[r] + i] = p;
            atomicAdd(&cnt[(p >> 24) * R + ((p & 0xFFFFFFu) >> RSH)], 1);
        }
    }
    __syncthreads();
    int loc[R];
    int s = 0;
#pragma unroll
    for (int i = 0; i < R; i++) { loc[i] = s; s += cnt[tid * R + i]; }
    psum[tid] = s;
    __syncthreads();
    for (int off = 1; off < NPB; off <<= 1) {
        int a = (tid >= off) ? psum[tid - off] : 0;
        __syncthreads();
        psum[tid] += a;
        __syncthreads();
    }
    int excl = psum[tid] - s;
#pragma unroll
    for (int i = 0; i < R; i++) cur[tid * R + i] = excl + loc[i];
    {
        int n = b * NPB + tid;
        if (n < N) {
            rowptr[n] = b * BSTRIDE + excl;
            rowcnt[n] = s;
            dinv[n] = rsqrtf((float)s + 1.0f);
        }
    }
    __syncthreads();
    for (int i = tid; i < total; i += NT) {
        unsigned p = se[i];
        unsigned sidx = p & 0xFFFFFFu;
        int bin = (int)(p >> 24) * R + (int)(sidx >> RSH);
        int pos = atomicAdd(&cur[bin], 1);
        esrc[b * BSTRIDE + pos] = (int)sidx;
    }
}

// Layer 1 GEMM 165->32 via MFMA 16x16x32 bf16. One wave per 16-node tile,
// 4 tiles (64 nodes) per block. v4: x slab + W1^T staged into LDS COALESCED
// (bf16, rows padded to 200 -> 16B-aligned ds_read_b128 fragments).
__global__ __launch_bounds__(NT) void gemm1_mfma(
    const float* __restrict__ in, const float* __restrict__ W,
    const float* __restrict__ dinv, uint4* __restrict__ hs, int Ntot) {
    constexpr int DIN = 165;
    constexpr int RP = 200;                  // padded row length (bf16)
    __shared__ unsigned short xs[64 * RP];   // 25.6KB staged x slab
    __shared__ unsigned short ws[32 * RP];   // 12.8KB staged W1^T
    __shared__ float tile[4][16][36];        // 9.2KB epilogue transpose
    int ntiles = (Ntot + 15) >> 4;
    int slab0 = (blockIdx.x * 4) << 4;       // first node of this 64-row slab
    int rows = min(64, Ntot - slab0);
    // zero the pad zones (k in [165,200)) of xs and ws
    for (int i = threadIdx.x; i < (64 + 32) * (RP - DIN); i += NT) {
        int r = i / (RP - DIN);
        int k = DIN + (i - r * (RP - DIN));
        if (r < 64) xs[r * RP + k] = 0;
        else        ws[(r - 64) * RP + k] = 0;
    }
    // stage x rows: global idx linear (slab0*DIN + i) -> fully coalesced
    {
        const float* xbase = in + (size_t)slab0 * DIN;
        int tot = rows * DIN;
        for (int i = threadIdx.x; i < tot; i += NT) {
            int r = i / DIN;
            xs[i + r * (RP - DIN)] = f2bf(xbase[i]);
        }
    }
    // stage W1 transposed: read W[i] linear (i = k*32+col) -> coalesced
    for (int i = threadIdx.x; i < DIN * 32; i += NT) {
        int k = i >> 5;
        int col = i & 31;
        ws[col * RP + k] = f2bf(W[i]);
    }
    __syncthreads();
    int lane = threadIdx.x & 63;
    int wv = threadIdx.x >> 6;
    int t = blockIdx.x * 4 + wv;
    if (t >= ntiles) return;
    int n0 = t << 4;
    int mrow = lane & 15;
    int quad = lane >> 4;
    int arow = n0 + mrow;
    if (arow >= Ntot) arow = Ntot - 1;  // clamp (stays within staged slab)
    int lrow = arow - slab0;            // LDS row in [0,64)
    f32x4 acc0 = {0.f, 0.f, 0.f, 0.f};
    f32x4 acc1 = {0.f, 0.f, 0.f, 0.f};
#pragma unroll
    for (int c = 0; c < 6; c++) {
        int kb = c * 32 + quad * 8;     // max 184; [165,200) zero-padded
        union { bf16x8 v; unsigned short u[8]; } A, B0, B1;
        __builtin_memcpy(&A.v,  &xs[lrow * RP + kb], 16);
        __builtin_memcpy(&B0.v, &ws[mrow * RP + kb], 16);
        __builtin_memcpy(&B1.v, &ws[(16 + mrow) * RP + kb], 16);
        acc0 = __builtin_amdgcn_mfma_f32_16x16x32_bf16(A.v, B0.v, acc0, 0, 0, 0);
        acc1 = __builtin_amdgcn_mfma_f32_16x16x32_bf16(A.v, B1.v, acc1, 0, 0, 0);
    }
#pragma unroll
    for (int r = 0; r < 4; r++) {
        tile[wv][quad * 4 + r][mrow] = acc0[r];
        tile[wv][quad * 4 + r][16 + mrow] = acc1[r];
    }
    int node = lane >> 2;
    int part = lane & 3;          // features part*8 .. part*8+7
    int n = n0 + node;
    if (n >= Ntot) return;
    float dv = dinv[n];
    float f[8];
#pragma unroll
    for (int i = 0; i < 8; i++) f[i] = tile[wv][node][part * 8 + i];
    unsigned u0 = packbf(dv * f[0], dv * f[1]);
    unsigned u1 = packbf(dv * f[2], dv * f[3]);
    unsigned u2 = packbf(dv * f[4], dv * f[5]);
    unsigned u3 = packbf(dv * f[6], dv * f[7]);
    hs[(size_t)n * 4 + part] = make_uint4(u0, u1, u2, u3);
}

// Fused layer-1 gather + relu(dv*agg+b1) + 32->16 GEMM + bf16 message pack.
// 4 lanes/node: c = feature half (2 uint4 = 32B), h = edge half. The two
// c-lanes of a half share each 64B line. h-combine shfl_xor(a,2) pre-relu;
// feature-half GEMM partials combine via shfl_xor(z,1). Free-running (MLP
// maximal — locality schemes proven net-negative here, r15-r17/r22).
__global__ __launch_bounds__(NT) void g1g2_kernel(
    const uint4* __restrict__ hsb, const int* __restrict__ esrc,
    const int* __restrict__ rowptr, const int* __restrict__ rowcnt,
    const float* __restrict__ dinv, const float* __restrict__ b1,
    const float* __restrict__ W2 /*[32][16]*/, uint4* __restrict__ hs2b,
    int N) {
    __shared__ float sW[32 * 16];
    __shared__ float sb[32];
    for (int i = threadIdx.x; i < 32 * 16; i += NT) sW[i] = W2[i];
    if (threadIdx.x < 32) sb[threadIdx.x] = b1[threadIdx.x];
    __syncthreads();
    int gid = blockIdx.x * NT + threadIdx.x;
    int n = gid >> 2;
    int q = gid & 3;
    int c = q & 1;
    int h = q >> 1;
    if (n >= N) return;
    int start = rowptr[n];
    int cnt = rowcnt[n];
    int half0 = (cnt + 1) >> 1;
    int j    = start + (h ? half0 : 0);
    int jend = start + (h ? cnt : half0);
    float a[16];
    if (h == 0) {  // self-loop message
        const uint4* hp = hsb + (size_t)n * 4 + c * 2;
        uint4 v0 = hp[0], v1 = hp[1];
        const unsigned* u0 = (const unsigned*)&v0;
        const unsigned* u1 = (const unsigned*)&v1;
#pragma unroll
        for (int w = 0; w < 4; w++) {
            unsigned lo = u0[w] << 16, hi = u0[w] & 0xffff0000u;
            a[2 * w] = *(float*)&lo; a[2 * w + 1] = *(float*)&hi;
            unsigned lo1 = u1[w] << 16, hi1 = u1[w] & 0xffff0000u;
            a[8 + 2 * w] = *(float*)&lo1; a[8 + 2 * w + 1] = *(float*)&hi1;
        }
    } else {
#pragma unroll
        for (int k = 0; k < 16; k++) a[k] = 0.f;
    }
    for (; j + 3 < jend; j += 4) {
        int s0 = esrc[j], s1 = esrc[j + 1], s2 = esrc[j + 2], s3 = esrc[j + 3];
        uint4 v00 = hsb[(size_t)s0 * 4 + c * 2], v01 = hsb[(size_t)s0 * 4 + c * 2 + 1];
        uint4 v10 = hsb[(size_t)s1 * 4 + c * 2], v11 = hsb[(size_t)s1 * 4 + c * 2 + 1];
        uint4 v20 = hsb[(size_t)s2 * 4 + c * 2], v21 = hsb[(size_t)s2 * 4 + c * 2 + 1];
        uint4 v30 = hsb[(size_t)s3 * 4 + c * 2], v31 = hsb[(size_t)s3 * 4 + c * 2 + 1];
        acc8(a, v00); acc8(a + 8, v01);
        acc8(a, v10); acc8(a + 8, v11);
        acc8(a, v20); acc8(a + 8, v21);
        acc8(a, v30); acc8(a + 8, v31);
    }
    for (; j < jend; j++) {
        int s = esrc[j];
        acc8(a, hsb[(size_t)s * 4 + c * 2]);
        acc8(a + 8, hsb[(size_t)s * 4 + c * 2 + 1]);
    }
    // combine edge halves (lane +-2): full aggregation before relu
#pragma unroll
    for (int k = 0; k < 16; k++) a[k] += __shfl_xor(a[k], 2);
    float dv = dinv[n];
    float z[16];
#pragma unroll
    for (int d = 0; d < 16; d++) z[d] = 0.f;
#pragma unroll
    for (int k = 0; k < 16; k++) {
        float f = fmaxf(fmaf(dv, a[k], sb[c * 16 + k]), 0.f);
#pragma unroll
        for (int d = 0; d < 16; d++)
            z[d] = fmaf(f, sW[(c * 16 + k) * 16 + d], z[d]);
    }
    // combine feature halves (lane +-1): full z on all 4 lanes
#pragma unroll
    for (int d = 0; d < 16; d++) z[d] += __shfl_xor(z[d], 1);
    if (h == 0) {  // lane c packs outputs c*8 .. c*8+7 (message = dv * z)
        unsigned u0 = packbf(dv * z[c * 8 + 0], dv * z[c * 8 + 1]);
        unsigned u1 = packbf(dv * z[c * 8 + 2], dv * z[c * 8 + 3]);
        unsigned u2 = packbf(dv * z[c * 8 + 4], dv * z[c * 8 + 5]);
        unsigned u3 = packbf(dv * z[c * 8 + 6], dv * z[c * 8 + 7]);
        hs2b[(size_t)n * 2 + c] = make_uint4(u0, u1, u2, u3);
    }
}

// Fused layer-2 gather + relu(dv*agg+b2) + 16->2 GEMM -> hs3 (f32 [N][2]).
// 8 lanes/node: c = feature half (one uint4; c-pair shares 32B), h = edge
// quarter (0..3). Table 3.2MB L2-resident -> latency-bound -> 2x concurrency
// (r14 mechanism). Combine quarters shfl_xor(a,2)+(a,4); c via shfl_xor(z,1).
__global__ __launch_bounds__(NT) void g2g3_kernel(
    const uint4* __restrict__ hs2b, const int* __restrict__ esrc,
    const int* __restrict__ rowptr, const int* __restrict__ rowcnt,
    const float* __restrict__ dinv, const float* __restrict__ b2,
    const float* __restrict__ W3 /*[16][2]*/, float* __restrict__ hs3,
    int N) {
    __shared__ float sW[32];
    __shared__ float sb[16];
    if (threadIdx.x < 32) sW[threadIdx.x] = W3[threadIdx.x];
    if (threadIdx.x < 16) sb[threadIdx.x] = b2[threadIdx.x];
    __syncthreads();
    int gid = blockIdx.x * NT + threadIdx.x;
    int n = gid >> 3;
    int q = gid & 7;
    int c = q & 1;
    int h = q >> 1;          // edge quarter
    if (n >= N) return;
    int start = rowptr[n];
    int cnt = rowcnt[n];
    int j    = start + ((h * cnt) >> 2);
    int jend = start + (((h + 1) * cnt) >> 2);
    float a[8];
    if (q < 2) {  // self-loop message on the h==0 c-pair
        uint4 v = hs2b[(size_t)n * 2 + c];
        const unsigned* u = (const unsigned*)&v;
#pragma unroll
        for (int w = 0; w < 4; w++) {
            unsigned lo = u[w] << 16, hi = u[w] & 0xffff0000u;
            a[2 * w] = *(float*)&lo; a[2 * w + 1] = *(float*)&hi;
        }
    } else {
#pragma unroll
        for (int k = 0; k < 8; k++) a[k] = 0.f;
    }
    for (; j + 3 < jend; j += 4) {
        uint4 v0 = hs2b[(size_t)esrc[j] * 2 + c];
        uint4 v1 = hs2b[(size_t)esrc[j + 1] * 2 + c];
        uint4 v2 = hs2b[(size_t)esrc[j + 2] * 2 + c];
        uint4 v3 = hs2b[(size_t)esrc[j + 3] * 2 + c];
        acc8(a, v0); acc8(a, v1); acc8(a, v2); acc8(a, v3);
    }
    for (; j < jend; j++) acc8(a, hs2b[(size_t)esrc[j] * 2 + c]);
    // combine edge quarters (lanes +-2, +-4) before relu
#pragma unroll
    for (int k = 0; k < 8; k++) a[k] += __shfl_xor(a[k], 2);
#pragma unroll
    for (int k = 0; k < 8; k++) a[k] += __shfl_xor(a[k], 4);
    float dv = dinv[n];
    float z0 = 0.f, z1 = 0.f;
#pragma unroll
    for (int k = 0; k < 8; k++) {
        float f = fmaxf(fmaf(dv, a[k], sb[c * 8 + k]), 0.f);
        z0 = fmaf(f, sW[(c * 8 + k) * 2 + 0], z0);
        z1 = fmaf(f, sW[(c * 8 + k) * 2 + 1], z1);
    }
    z0 += __shfl_xor(z0, 1);
    z1 += __shfl_xor(z1, 1);
    if (q == 0) {
        hs3[(size_t)n * 2 + 0] = dv * z0;
        hs3[(size_t)n * 2 + 1] = dv * z1;
    }
}

// Layer 3 gather (hs3 0.8MB, L2-resident) + bias + log_softmax.
// 4 lanes/node, edge quarters, shfl_xor(1)+(2) combine.
__global__ __launch_bounds__(NT) void final_kernel(
    const float* __restrict__ hs3, const int* __restrict__ esrc,
    const int* __restrict__ rowptr, const int* __restrict__ rowcnt,
    const float* __restrict__ dinv, const float* __restrict__ b,
    float* __restrict__ out, int N) {
    int gid = blockIdx.x * NT + threadIdx.x;
    int n = gid >> 2;
    int h = gid & 3;         // edge quarter
    if (n >= N) return;
    int start = rowptr[n];
    int cnt = rowcnt[n];
    int j    = start + ((h * cnt) >> 2);
    int jend = start + (((h + 1) * cnt) >> 2);
    const float2* h2 = (const float2*)hs3;
    float2 acc = h ? make_float2(0.f, 0.f) : h2[n];  // self-loop on h=0
    for (; j + 3 < jend; j += 4) {
        float2 v0 = h2[esrc[j]], v1 = h2[esrc[j + 1]];
        float2 v2 = h2[esrc[j + 2]], v3 = h2[esrc[j + 3]];
        acc.x += v0.x + v1.x + v2.x + v3.x;
        acc.y += v0.y + v1.y + v2.y + v3.y;
    }
    for (; j < jend; j++) {
        float2 v = h2[esrc[j]];
        acc.x += v.x; acc.y += v.y;
    }
    acc.x += __shfl_xor(acc.x, 1);
    acc.y += __shfl_xor(acc.y, 1);
    acc.x += __shfl_xor(acc.x, 2);
    acc.y += __shfl_xor(acc.y, 2);
    if (h == 0) {
        float dv = dinv[n];
        float z0 = fmaf(dv, acc.x, b[0]);
        float z1 = fmaf(dv, acc.y, b[1]);
        float m = fmaxf(z0, z1);
        float lse = m + logf(expf(z0 - m) + expf(z1 - m));
        out[(size_t)n * 2 + 0] = z0 - lse;
        out[(size_t)n * 2 + 1] = z1 - lse;
    }
}

extern "C" void kernel_launch(void* const* d_in, const int* in_sizes, int n_in,
                              void* d_out, int out_size, void* d_ws, size_t ws_size,
                              hipStream_t stream) {
    const float* x  = (const float*)d_in[0];
    const int*   ei = (const int*)d_in[1];
    const float* W1 = (const float*)d_in[2];
    const float* b1 = (const float*)d_in[3];
    const float* W2 = (const float*)d_in[4];
    const float* b2 = (const float*)d_in[5];
    const float* W3 = (const float*)d_in[6];
    const float* b3 = (const float*)d_in[7];
    float* out = (float*)d_out;

    const int N = in_sizes[0] / 165;  // 100000
    const int E = in_sizes[1] / 2;    // 3200000
    const int* src = ei;
    const int* dst = ei + E;
    const int nbuk = (N + NPB - 1) >> LOG_NPB;  // 391
    const int G8 = ((size_t)N * 8 + NT - 1) / NT;  // 8 lanes/node
    const int G4 = ((size_t)N * 4 + NT - 1) / NT;  // 4 lanes/node

    char* p = (char*)d_ws;
    int* cursor8   = (int*)p;      p += (size_t)NREP * MAXBUK * 4;
    unsigned* ebuf = (unsigned*)p; p += (size_t)nbuk * BSTRIDE * 4;
    int* esrc      = (int*)p;      p += (size_t)nbuk * BSTRIDE * 4;
    int* rowptr    = (int*)p;      p += (size_t)N * 4;
    int* rowcnt    = (int*)p;      p += (size_t)N * 4;
    float* dinv    = (float*)p;    p += (size_t)N * 4;
    uint4* hs1b    = (uint4*)p;    p += (size_t)N * 4 * 16;  // bf16 [N][4]uint4
    uint4* hs2b    = (uint4*)p;    p += (size_t)N * 2 * 16;  // bf16 [N][2]uint4
    float* hs3     = (float*)p;    p += (size_t)N * 2 * 4;   // f32 [N][2]

    (void)hipMemsetAsync(cursor8, 0, (size_t)NREP * MAXBUK * sizeof(int), stream);
    place_kernel<<<(E + EPB_B - 1) / EPB_B, NT, 0, stream>>>(src, dst, cursor8, ebuf, E, nbuk);
    sort_kernel<<<nbuk, NT, 0, stream>>>(ebuf, cursor8, esrc, rowptr, rowcnt, dinv, N);

    // Layer 1: 165 -> 32 MFMA, bf16 messages (one 64B line per node)
    gemm1_mfma<<<((N + 15) / 16 + 3) / 4, NT, 0, stream>>>(x, W1, dinv, hs1b, N);

    // Layer 1 gather + layer 2 GEMM fused (4 lanes/node, free-running)
    g1g2_kernel<<<G4, NT, 0, stream>>>(hs1b, esrc, rowptr, rowcnt, dinv, b1, W2, hs2b, N);

    // Layer 2 gather + layer 3 GEMM fused (8 lanes/node)
    g2g3_kernel<<<G8, NT, 0, stream>>>(hs2b, esrc, rowptr, rowcnt, dinv, b2, W3, hs3, N);

    // Layer 3 gather + bias + log_softmax (4 lanes/node)
    final_kernel<<<G4, NT, 0, stream>>>(hs3, esrc, rowptr, rowcnt, dinv, b3, out, N);
}